// Round 6
// baseline (492.561 us; speedup 1.0000x reference)
//
#include <hip/hip_runtime.h>

#define SS 4
#define NH 6
#define NWIN 2048

typedef unsigned short u16;
typedef __attribute__((ext_vector_type(8))) short bf8;
typedef __attribute__((ext_vector_type(4))) float f4;

__device__ __forceinline__ u16 f2bf(float f) {
  unsigned int x = __builtin_bit_cast(unsigned int, f);
  unsigned int r = x + 0x7fffu + ((x >> 16) & 1u);
  return (u16)(r >> 16);
}
__device__ __forceinline__ unsigned int pk2(float a, float b) {
  return (unsigned int)f2bf(a) | ((unsigned int)f2bf(b) << 16);
}

// Inline exact-GELU (Abramowitz-Stegun 7.1.26 erf, |err|<=1.5e-7): pure VALU.
__device__ __forceinline__ float gelu_exact(float v) {
  float u = v * 0.70710678118654752f;
  float a = __builtin_fabsf(u);
  float t = __builtin_amdgcn_rcpf(1.f + 0.3275911f * a);
  float poly = t * (0.254829592f + t * (-0.284496736f + t * (1.421413741f +
               t * (-1.453152027f + t * 1.061405429f))));
  float e = __expf(-a * a);
  float erf_a = 1.f - poly * e;
  float erf_u = (u < 0.f) ? -erf_a : erf_a;
  return 0.5f * v * (1.f + erf_u);
}

// LDS read helper: byte-offset addressing (offsets are 16B-aligned)
#define LDSB(base, off) (*(const bf8*)((const char*)(base) + (off)))

// Build an A/B-fragment (row = lr, k = quad*8 + e) from quad-transposed
// register state (verified-passing layout, r1).
__device__ __forceinline__ bf8 fragq(unsigned p00, unsigned p01,
                                     unsigned p10, unsigned p11,
                                     int L0, int L1, bool selhi) {
  unsigned a0 = (unsigned)__shfl((int)p00, L0);
  unsigned a1 = (unsigned)__shfl((int)p01, L0);
  unsigned b0 = (unsigned)__shfl((int)p10, L0);
  unsigned b1 = (unsigned)__shfl((int)p11, L0);
  unsigned c0 = (unsigned)__shfl((int)p00, L1);
  unsigned c1 = (unsigned)__shfl((int)p01, L1);
  unsigned d0 = (unsigned)__shfl((int)p10, L1);
  unsigned d1 = (unsigned)__shfl((int)p11, L1);
  uint4 t;
  t.x = selhi ? b0 : a0;
  t.y = selhi ? b1 : a1;
  t.z = selhi ? d0 : c0;
  t.w = selhi ? d1 : c1;
  return __builtin_bit_cast(bf8, t);
}

// ---- prep A: f32 [192][N] -> bf16 "LDS image": row n, byte col swizzled by
// ((n&7)<<4). Staging is a LINEAR DMA; compute reads keep the XOR. ----
__global__ __launch_bounds__(256) void k_prep_row(
    const float* __restrict__ src, u16* __restrict__ dst,
    int N, int scale_n, float scale)
{
  int idx = blockIdx.x * 256 + threadIdx.x;
  int total = 48 * N;                 // 192/4 groups per row
  if (idx >= total) return;
  int n = idx % N;
  int kq = (idx / N) << 2;
  float s = (n < scale_n) ? scale : 1.f;
  ushort4 o;
  o.x = f2bf(src[(size_t)(kq + 0) * N + n] * s);
  o.y = f2bf(src[(size_t)(kq + 1) * N + n] * s);
  o.z = f2bf(src[(size_t)(kq + 2) * N + n] * s);
  o.w = f2bf(src[(size_t)(kq + 3) * N + n] * s);
  int byte_off = n * 384 + ((kq * 2) ^ ((n & 7) << 4));
  *(ushort4*)((char*)dst + byte_off) = o;
}

// ---- prep B: fc2_w f32 [768][192] -> 24 half-slabs of 12288 B; slab s =
// Wl2h rows [192][64B] (k-cols s*32..s*32+31), XOR ((n&3)<<4). ----
__global__ __launch_bounds__(256) void k_prep_fc2(
    const float* __restrict__ src, u16* __restrict__ dst)
{
  int idx = blockIdx.x * 256 + threadIdx.x;
  if (idx >= 192 * 192) return;       // 192 rows x 192 groups of 4 (768 k)
  int n = idx % 192;
  int kq = (idx / 192) << 2;
  ushort4 o;
  o.x = f2bf(src[(size_t)(kq + 0) * 192 + n]);
  o.y = f2bf(src[(size_t)(kq + 1) * 192 + n]);
  o.z = f2bf(src[(size_t)(kq + 2) * 192 + n]);
  o.w = f2bf(src[(size_t)(kq + 3) * 192 + n]);
  int cc = kq * 2;                    // byte col within the 1536B logical row
  int byte_off = (cc >> 6) * 12288 + n * 64 + ((cc & 63) ^ ((n & 3) << 4));
  *(ushort4*)((char*)dst + byte_off) = o;
}

// ---- K1: roll+partition+QKV+attention+proj+reverse+roll+residual ----
// Phase pipeline: per phase, (1) issue next half-slab DMA into the other
// WtB buffer, (2) compute current buffer, (3) one __syncthreads (its vmcnt(0)
// drain lands a full phase after issue -> latency hidden). 18 QKV + 6 proj
// phases of 32 out-chans. LDS 72KB -> 2 blocks/CU.
__global__ __launch_bounds__(256, 2) void k_win(
    const float* __restrict__ x, const u16* __restrict__ qkvT,
    const float* __restrict__ qkv_b, const float* __restrict__ rpb,
    const u16* __restrict__ projT, const float* __restrict__ proj_b,
    float* __restrict__ out)
{
  __shared__ short KsB[64 * 192];     // K [token][chan], rows 384B, swizzled
  __shared__ short VtB[192 * 64];     // V^T [chan][token], rows 128B, swizzled
  __shared__ short WtB[2][32 * 192];  // half-slab dbuf, 2 x 12KB

  const int w = blockIdx.x;
  const int b = w >> 6, wh = (w >> 3) & 7, wwi = w & 7;
  const int tid = threadIdx.x;
  const int wave = tid >> 6, lane = tid & 63, quad = lane >> 4, lr = lane & 15;
  const int L0 = (quad & 1) * 32 + lr, L1 = L0 + 16;
  const bool selhi = (quad >> 1) != 0;
  const int xlr = (lr & 7) << 4;

  const char* qkvB = (const char*)qkvT;
  const char* projB = (const char*)projT;
  const int a0 = tid * 16;

  auto issue = [&](const char* src, int buf) {
#pragma unroll
    for (int i = 0; i < 3; ++i)
      __builtin_amdgcn_global_load_lds(
          (const unsigned int*)(src + a0 + i * 4096),
          (unsigned int*)((char*)WtB[buf] + a0 + i * 4096), 16, 0, 0);
  };

  // prologue: issue phase 0 before the x loads (latency hides under them)
  issue(qkvB, 0);

  // Phase A: A-fragments of rolled window straight into registers
  bf8 af[6];
  {
    int token = wave * 16 + lr;
    int hs = (wh * 8 + (token >> 3) + SS) & 63;
    int ws2 = (wwi * 8 + (token & 7) + SS) & 63;
    const float* base = x + ((size_t)b * 4096 + hs * 64 + ws2) * 192 + quad * 8;
#pragma unroll
    for (int kc = 0; kc < 6; ++kc) {
      float4 lo = *(const float4*)(base + kc * 32);
      float4 hi = *(const float4*)(base + kc * 32 + 4);
      bf8 v;
      v[0] = (short)f2bf(lo.x); v[1] = (short)f2bf(lo.y);
      v[2] = (short)f2bf(lo.z); v[3] = (short)f2bf(lo.w);
      v[4] = (short)f2bf(hi.x); v[5] = (short)f2bf(hi.y);
      v[6] = (short)f2bf(hi.z); v[7] = (short)f2bf(hi.w);
      af[kc] = v;
    }
  }

  __syncthreads();   // phase-0 buffer ready

  const float scale = 0.17677669529663687f;

  // Q phases 0..5 (32 chans each -> one qf frag per phase)
  bf8 qf[6];
#pragma unroll
  for (int p = 0; p < 6; ++p) {
    issue(qkvB + (size_t)(p + 1) * 12288, (p + 1) & 1);
    f4 qa[2];
#pragma unroll
    for (int i = 0; i < 2; ++i) qa[i] = (f4){0.f, 0.f, 0.f, 0.f};
#pragma unroll
    for (int kc = 0; kc < 6; ++kc)
#pragma unroll
      for (int nt = 0; nt < 2; ++nt) {
        bf8 wf = LDSB(WtB[p & 1], (nt * 16 + lr) * 384 + ((kc * 64 + quad * 16) ^ xlr));
        qa[nt] = __builtin_amdgcn_mfma_f32_16x16x32_bf16(wf, af[kc], qa[nt], 0, 0, 0);
      }
    unsigned pq[2][2];
#pragma unroll
    for (int nt = 0; nt < 2; ++nt) {
      float4 bv = *(const float4*)(qkv_b + p * 32 + nt * 16 + quad * 4);
      pq[nt][0] = pk2(qa[nt][0] + bv.x * scale, qa[nt][1] + bv.y * scale);
      pq[nt][1] = pk2(qa[nt][2] + bv.z * scale, qa[nt][3] + bv.w * scale);
    }
    qf[p] = fragq(pq[0][0], pq[0][1], pq[1][0], pq[1][1], L0, L1, selhi);
    __syncthreads();
  }

  // K phases 6..11 -> swizzled Ks[token][chan]
  for (int s2 = 0; s2 < 6; ++s2) {
    int g = 6 + s2;
    issue(qkvB + (size_t)(g + 1) * 12288, (g + 1) & 1);
    f4 ka[2];
#pragma unroll
    for (int i = 0; i < 2; ++i) ka[i] = (f4){0.f, 0.f, 0.f, 0.f};
#pragma unroll
    for (int kc = 0; kc < 6; ++kc)
#pragma unroll
      for (int nt = 0; nt < 2; ++nt) {
        bf8 wf = LDSB(WtB[g & 1], (nt * 16 + lr) * 384 + ((kc * 64 + quad * 16) ^ xlr));
        ka[nt] = __builtin_amdgcn_mfma_f32_16x16x32_bf16(wf, af[kc], ka[nt], 0, 0, 0);
      }
#pragma unroll
    for (int nt = 0; nt < 2; ++nt) {
      float4 bv = *(const float4*)(qkv_b + 192 + s2 * 32 + nt * 16 + quad * 4);
      uint2 st;
      st.x = pk2(ka[nt][0] + bv.x, ka[nt][1] + bv.y);
      st.y = pk2(ka[nt][2] + bv.z, ka[nt][3] + bv.w);
      *(uint2*)((char*)KsB + (wave * 16 + lr) * 384 +
                ((s2 * 64 + nt * 32 + quad * 8) ^ xlr)) = st;
    }
    __syncthreads();
  }

  // V phases 12..17 -> swizzled Vt[chan][token]; phase 17 prefetches proj0
  for (int s2 = 0; s2 < 6; ++s2) {
    int g = 12 + s2;
    issue(g < 17 ? qkvB + (size_t)(g + 1) * 12288 : projB, (g + 1) & 1);
    f4 va[2];
#pragma unroll
    for (int i = 0; i < 2; ++i) va[i] = (f4){0.f, 0.f, 0.f, 0.f};
#pragma unroll
    for (int kc = 0; kc < 6; ++kc)
#pragma unroll
      for (int nt = 0; nt < 2; ++nt) {
        bf8 wf = LDSB(WtB[g & 1], (nt * 16 + lr) * 384 + ((kc * 64 + quad * 16) ^ xlr));
        va[nt] = __builtin_amdgcn_mfma_f32_16x16x32_bf16(af[kc], wf, va[nt], 0, 0, 0);
      }
#pragma unroll
    for (int nt = 0; nt < 2; ++nt) {
      float bias = qkv_b[384 + s2 * 32 + nt * 16 + lr];
      uint2 st;
      st.x = pk2(va[nt][0] + bias, va[nt][1] + bias);
      st.y = pk2(va[nt][2] + bias, va[nt][3] + bias);
      *(uint2*)((char*)VtB + (size_t)(s2 * 32 + nt * 16 + lr) * 128 +
                ((wave * 32 + quad * 8) ^ xlr)) = st;
    }
    __syncthreads();
  }

  // Phase C: attention, fully in-register softmax (query = lr)
  const int q_tok = wave * 16 + lr;
  const int qh3 = q_tok >> 3, qw3 = q_tok & 7;
  int lab_q;
  {
    int ph_r = wh * 8 + qh3, pw_r = wwi * 8 + qw3;
    lab_q = (ph_r < 56 ? 0 : (ph_r < 60 ? 1 : 2)) * 3 +
            (pw_r < 56 ? 0 : (pw_r < 60 ? 1 : 2));
  }
  int ridx[4][4]; float msk[4][4];
#pragma unroll
  for (int nt = 0; nt < 4; ++nt)
#pragma unroll
    for (int r = 0; r < 4; ++r) {
      int key = nt * 16 + quad * 4 + r;
      int kh = key >> 3, kw = key & 7;
      ridx[nt][r] = ((qh3 - kh + 7) * 15 + (qw3 - kw + 7)) * NH;
      int ph_c = wh * 8 + kh, pw_c = wwi * 8 + kw;
      int lab_k = (ph_c < 56 ? 0 : (ph_c < 60 ? 1 : 2)) * 3 +
                  (pw_c < 56 ? 0 : (pw_c < 60 ? 1 : 2));
      msk[nt][r] = (lab_q != lab_k) ? -100.f : 0.f;
    }

  unsigned obf[6][4];
#pragma unroll
  for (int h = 0; h < 6; ++h) {
    f4 sa[4];
#pragma unroll
    for (int i = 0; i < 4; ++i) sa[i] = (f4){0.f, 0.f, 0.f, 0.f};
#pragma unroll
    for (int nt = 0; nt < 4; ++nt) {
      bf8 kfr = LDSB(KsB, (nt * 16 + lr) * 384 + ((h * 64 + quad * 16) ^ xlr));
      sa[nt] = __builtin_amdgcn_mfma_f32_16x16x32_bf16(kfr, qf[h], sa[nt], 0, 0, 0);
    }
    float p[4][4]; float mx = -1e30f;
#pragma unroll
    for (int nt = 0; nt < 4; ++nt)
#pragma unroll
      for (int r = 0; r < 4; ++r) {
        float v = sa[nt][r] + rpb[ridx[nt][r] + h] + msk[nt][r];
        p[nt][r] = v; mx = fmaxf(mx, v);
      }
    mx = fmaxf(mx, __shfl_xor(mx, 16));
    mx = fmaxf(mx, __shfl_xor(mx, 32));
    float sum = 0.f;
#pragma unroll
    for (int nt = 0; nt < 4; ++nt)
#pragma unroll
      for (int r = 0; r < 4; ++r) {
        float e = __expf(p[nt][r] - mx);
        p[nt][r] = e; sum += e;
      }
    sum += __shfl_xor(sum, 16);
    sum += __shfl_xor(sum, 32);
    float inv = 1.f / sum;
    unsigned pp[4][2];
#pragma unroll
    for (int nt = 0; nt < 4; ++nt) {
      pp[nt][0] = pk2(p[nt][0] * inv, p[nt][1] * inv);
      pp[nt][1] = pk2(p[nt][2] * inv, p[nt][3] * inv);
    }
    f4 o0 = (f4){0.f, 0.f, 0.f, 0.f}, o1 = (f4){0.f, 0.f, 0.f, 0.f};
#pragma unroll
    for (int kc = 0; kc < 2; ++kc) {
      bf8 pf = fragq(pp[kc * 2][0], pp[kc * 2][1],
                     pp[kc * 2 + 1][0], pp[kc * 2 + 1][1], L0, L1, selhi);
      bf8 v0 = LDSB(VtB, (size_t)(h * 32 + lr) * 128 + ((kc * 64 + quad * 16) ^ xlr));
      bf8 v1 = LDSB(VtB, (size_t)(h * 32 + 16 + lr) * 128 + ((kc * 64 + quad * 16) ^ xlr));
      o0 = __builtin_amdgcn_mfma_f32_16x16x32_bf16(v0, pf, o0, 0, 0, 0);
      o1 = __builtin_amdgcn_mfma_f32_16x16x32_bf16(v1, pf, o1, 0, 0, 0);
    }
    obf[h][0] = pk2(o0[0], o0[1]); obf[h][1] = pk2(o0[2], o0[3]);
    obf[h][2] = pk2(o1[0], o1[1]); obf[h][3] = pk2(o1[2], o1[3]);
  }

  // Phase D: proj phases 18..23 (buf0 for p=0 was staged at phase 17)
  bf8 of[6];
#pragma unroll
  for (int kc = 0; kc < 6; ++kc)
    of[kc] = fragq(obf[kc][0], obf[kc][1], obf[kc][2], obf[kc][3], L0, L1, selhi);

  for (int p = 0; p < 6; ++p) {
    int g = 18 + p;
    if (p < 5) issue(projB + (size_t)(p + 1) * 12288, (g + 1) & 1);
    f4 acc[2];
#pragma unroll
    for (int i = 0; i < 2; ++i) acc[i] = (f4){0.f, 0.f, 0.f, 0.f};
#pragma unroll
    for (int kc = 0; kc < 6; ++kc)
#pragma unroll
      for (int nt = 0; nt < 2; ++nt) {
        bf8 wf = LDSB(WtB[g & 1], (nt * 16 + lr) * 384 + ((kc * 64 + quad * 16) ^ xlr));
        acc[nt] = __builtin_amdgcn_mfma_f32_16x16x32_bf16(of[kc], wf, acc[nt], 0, 0, 0);
      }
#pragma unroll
    for (int nt = 0; nt < 2; ++nt) {
      int c = p * 32 + nt * 16 + lr;
      float bias = proj_b[c];
#pragma unroll
      for (int r = 0; r < 4; ++r) {
        int row = wave * 16 + quad * 4 + r;
        int ho = (wh * 8 + (row >> 3) + SS) & 63;
        int wo = (wwi * 8 + (row & 7) + SS) & 63;
        size_t off = ((size_t)b * 4096 + ho * 64 + wo) * 192 + c;
        out[off] = acc[nt][r] + bias + x[off];
      }
    }
    __syncthreads();
  }
}

// ---- K2: fused FC1+GELU+FC2+residual ----
// 24 half-slab phases (32 hchans), dbuf'd Wl1h/Wl2h, issue-early single
// barrier per phase. LDS 48KB -> 3 blocks/CU.
__global__ __launch_bounds__(256, 3) void k_mlp(
    const u16* __restrict__ fc1T, const float* __restrict__ fc1_b,
    const u16* __restrict__ fc2T, const float* __restrict__ fc2_b,
    float* __restrict__ out)
{
  __shared__ short Wl1h[2][32 * 192];   // fc1 half-slab [32][384B], 12KB each
  __shared__ short Wl2h[2][192 * 32];   // fc2 half-slab [192][64B], 12KB each

  const int blk = blockIdx.x;
  const int tid = threadIdx.x;
  const int wave = tid >> 6, lane = tid & 63, quad = lane >> 4, lr = lane & 15;
  const int L0 = (quad & 1) * 32 + lr, L1 = L0 + 16;
  const bool selhi = (quad >> 1) != 0;
  const int xlr = (lr & 7) << 4;
  const int xl2 = (lr & 3) << 4;
  const size_t r0 = (size_t)blk * 64;

  const char* fc1B = (const char*)fc1T;
  const char* fc2B = (const char*)fc2T;
  const int a0 = tid * 16;

  auto issue = [&](int s, int buf) {
#pragma unroll
    for (int i = 0; i < 3; ++i) {
      __builtin_amdgcn_global_load_lds(
          (const unsigned int*)(fc1B + (size_t)s * 12288 + a0 + i * 4096),
          (unsigned int*)((char*)Wl1h[buf] + a0 + i * 4096), 16, 0, 0);
      __builtin_amdgcn_global_load_lds(
          (const unsigned int*)(fc2B + (size_t)s * 12288 + a0 + i * 4096),
          (unsigned int*)((char*)Wl2h[buf] + a0 + i * 4096), 16, 0, 0);
    }
  };

  issue(0, 0);   // prologue: phase-0 loads hide under the x1 loads

  // A-fragments of x1 straight from global (f32 -> bf16 regs)
  bf8 af[6];
  {
    const float* base = out + (r0 + wave * 16 + lr) * 192 + quad * 8;
#pragma unroll
    for (int kc = 0; kc < 6; ++kc) {
      float4 lo = *(const float4*)(base + kc * 32);
      float4 hi = *(const float4*)(base + kc * 32 + 4);
      bf8 v;
      v[0] = (short)f2bf(lo.x); v[1] = (short)f2bf(lo.y);
      v[2] = (short)f2bf(lo.z); v[3] = (short)f2bf(lo.w);
      v[4] = (short)f2bf(hi.x); v[5] = (short)f2bf(hi.y);
      v[6] = (short)f2bf(hi.z); v[7] = (short)f2bf(hi.w);
      af[kc] = v;
    }
  }

  f4 acc2[12];
#pragma unroll
  for (int i = 0; i < 12; ++i) acc2[i] = (f4){0.f, 0.f, 0.f, 0.f};

  __syncthreads();   // phase-0 buffers ready

#pragma unroll 1
  for (int s = 0; s < 24; ++s) {
    if (s < 23) issue(s + 1, (s + 1) & 1);

    // FC1 half-slab, SWAPPED -> H^T[hchan][token=lr] (32 hchans)
    f4 ha[2];
#pragma unroll
    for (int i = 0; i < 2; ++i) ha[i] = (f4){0.f, 0.f, 0.f, 0.f};
#pragma unroll
    for (int kc = 0; kc < 6; ++kc)
#pragma unroll
      for (int nt = 0; nt < 2; ++nt) {
        bf8 wf = LDSB(Wl1h[s & 1], (nt * 16 + lr) * 384 + ((kc * 64 + quad * 16) ^ xlr));
        ha[nt] = __builtin_amdgcn_mfma_f32_16x16x32_bf16(wf, af[kc], ha[nt], 0, 0, 0);
      }
    unsigned hp[2][2];
#pragma unroll
    for (int nt = 0; nt < 2; ++nt) {
      float4 bv = *(const float4*)(fc1_b + s * 32 + nt * 16 + quad * 4);
      float g0 = gelu_exact(ha[nt][0] + bv.x);
      float g1 = gelu_exact(ha[nt][1] + bv.y);
      float g2_ = gelu_exact(ha[nt][2] + bv.z);
      float g3 = gelu_exact(ha[nt][3] + bv.w);
      hp[nt][0] = pk2(g0, g1);
      hp[nt][1] = pk2(g2_, g3);
    }
    // FC2 partial accumulation over this 32-wide K half-slab
    bf8 hf = fragq(hp[0][0], hp[0][1], hp[1][0], hp[1][1], L0, L1, selhi);
#pragma unroll
    for (int nto = 0; nto < 12; ++nto) {
      bf8 wf = LDSB(Wl2h[s & 1], (nto * 16 + lr) * 64 + ((quad * 16) ^ xl2));
      acc2[nto] = __builtin_amdgcn_mfma_f32_16x16x32_bf16(hf, wf, acc2[nto], 0, 0, 0);
    }
    __syncthreads();
  }

  // epilogue: + bias + residual (f32 re-read), in-place
#pragma unroll
  for (int nt = 0; nt < 12; ++nt) {
    int c = nt * 16 + lr;
    float bias = fc2_b[c];
#pragma unroll
    for (int r = 0; r < 4; ++r) {
      int row = wave * 16 + quad * 4 + r;
      size_t off = (r0 + row) * 192 + c;
      out[off] = acc2[nt][r] + bias + out[off];
    }
  }
}

extern "C" void kernel_launch(void* const* d_in, const int* in_sizes, int n_in,
                              void* d_out, int out_size, void* d_ws, size_t ws_size,
                              hipStream_t stream)
{
  const float* x      = (const float*)d_in[0];
  const float* rpb    = (const float*)d_in[1];
  const float* qkv_w  = (const float*)d_in[2];
  const float* qkv_b  = (const float*)d_in[3];
  const float* proj_w = (const float*)d_in[4];
  const float* proj_b = (const float*)d_in[5];
  const float* fc1_w  = (const float*)d_in[6];
  const float* fc1_b  = (const float*)d_in[7];
  const float* fc2_w  = (const float*)d_in[8];
  const float* fc2_b  = (const float*)d_in[9];
  float* out = (float*)d_out;

  // bf16 weight LDS-images in workspace (885 KB total)
  u16* qkvT = (u16*)d_ws;                 // [576][384B] row-swizzled image
  u16* projT = qkvT + 576 * 192;          // [192][384B] image
  u16* fc1T  = projT + 192 * 192;         // [768][384B] image
  u16* fc2T  = fc1T + 768 * 192;          // 24 half-slabs x [192][64B] image

  const float scale = 0.17677669529663687f;  // 32^-0.5 baked into W_q
  k_prep_row<<<108, 256, 0, stream>>>(qkv_w, qkvT, 576, 192, scale);
  k_prep_row<<< 36, 256, 0, stream>>>(proj_w, projT, 192, 0, 1.f);
  k_prep_row<<<144, 256, 0, stream>>>(fc1_w, fc1T, 768, 0, 1.f);
  k_prep_fc2<<<144, 256, 0, stream>>>(fc2_w, fc2T);

  k_win<<<dim3(NWIN), 256, 0, stream>>>(x, qkvT, qkv_b, rpb, projT, proj_b, out);
  k_mlp<<<dim3(NWIN), 256, 0, stream>>>(fc1T, fc1_b, fc2T, fc2_b, out);
}